// Round 5
// baseline (84.288 us; speedup 1.0000x reference)
//
#include <hip/hip_runtime.h>

// Mamba-2 SSD forward. B=2, L=4096, H=16, P=S=64, chunk=64, n=64 chunks.
// K1: per chunk: M = L∘(C·B^T), Cs = dfs∘C, h_final^T, chunk log-decay.
//     All ws tiles stored in MFMA-fragment-native order (coalesced both ways).
// K2: h_inter = W_strict · h_final as a per-(bh,p) 64x64 triangular matmul (in-place).
// K3: LDS-free, barrier-free: Y^T = X^T·M^T + h^T·Cs^T, float4 stores.

#define BSZ 2
#define LSEQ 4096
#define NH 16
#define NC 64
#define NCH (BSZ * NH * NC)      // 2048 chunk tasks
#define CHW 4096                 // ushort elems per chunk ws tile
#define TILE_USHORTS ((size_t)NCH * CHW)

typedef float f32x4 __attribute__((ext_vector_type(4)));
typedef __bf16 bf16x8 __attribute__((ext_vector_type(8)));

union FragU { uint4 u; bf16x8 b; unsigned short s[8]; };

__device__ __forceinline__ unsigned short f2b(float x) {
    union { float f; unsigned u; } c; c.f = x;
    unsigned r = c.u + 0x7fffu + ((c.u >> 16) & 1u);   // RNE bf16
    return (unsigned short)(r >> 16);
}

// LDS element-index swizzles, 64 ushort per row
__device__ __forceinline__ int rm_e(int row, int k) { return row * 64 + (k ^ ((row & 7) << 3)); }
__device__ __forceinline__ int tr_e(int row, int k) { return row * 64 + (k ^ (((row >> 1) & 7) << 3)); }

__device__ __forceinline__ bf16x8 frag_rm(const unsigned short* buf, int tile, int kk, int l) {
    FragU f; f.u = *(const uint4*)&buf[rm_e(tile * 16 + (l & 15), kk * 32 + ((l >> 4) << 3))];
    return f.b;
}
__device__ __forceinline__ bf16x8 frag_tr(const unsigned short* buf, int tile, int kk, int l) {
    FragU f; f.u = *(const uint4*)&buf[tr_e(tile * 16 + (l & 15), kk * 32 + ((l >> 4) << 3))];
    return f.b;
}

// ---------------- K1 ----------------
__global__ __launch_bounds__(256) void ssd_k1(
    const float* __restrict__ Xg, const float* __restrict__ Ag,
    const float* __restrict__ Bg, const float* __restrict__ Cg,
    unsigned short* __restrict__ hws, unsigned short* __restrict__ Mws,
    unsigned short* __restrict__ Csws, float* __restrict__ dws)
{
    __shared__ __align__(16) unsigned short sBrm[64 * 64];  // B [j][s]
    __shared__ __align__(16) unsigned short sCrm[64 * 64];  // C [i][s]
    __shared__ __align__(16) unsigned short sBt[64 * 64];   // B^T [s][c]
    __shared__ __align__(16) unsigned short sXt[64 * 64];   // (dte∘X)^T [p][c]
    __shared__ float sE[64], sR[64], sDte[64];

    const int tid = threadIdx.x;
    const int l = tid & 63;
    const int w = tid >> 6;
    const int n = blockIdx.x & (NC - 1);
    const int h = (blockIdx.x >> 6) & (NH - 1);
    const int b = blockIdx.x >> 10;
    const int row0 = b * LSEQ + n * 64;
    const unsigned chb = (unsigned)blockIdx.x * CHW;

    // issue global loads early
    float4 xv[4], bv[4], cv[4];
    const int p0 = (tid & 15) * 4;
    #pragma unroll
    for (int it = 0; it < 4; ++it) {
        const int c = (tid >> 4) + it * 16;
        const unsigned g = ((unsigned)(row0 + c) * NH + h) * 64 + p0;
        xv[it] = *(const float4*)&Xg[g];
        bv[it] = *(const float4*)&Bg[g];
        cv[it] = *(const float4*)&Cg[g];
    }
    // wave0: inclusive cumsum of A, decay factors
    if (tid < 64) {
        float a = Ag[(unsigned)(row0 + tid) * NH + h];
        #pragma unroll
        for (int off = 1; off < 64; off <<= 1) {
            float v = __shfl_up(a, off, 64);
            if (tid >= off) a += v;
        }
        const float a63 = __shfl(a, 63, 64);
        sE[tid] = __expf(a);
        sR[tid] = __expf(-a);
        sDte[tid] = __expf(a63 - a);
        if (tid == 63) dws[blockIdx.x] = a63;       // log chunk decay
    }
    __syncthreads();

    // stage LDS tiles + write Cs (= E[i]∘C) to ws in fragment-native order
    #pragma unroll
    for (int it = 0; it < 4; ++it) {
        const int c = (tid >> 4) + it * 16;
        const float dte = sDte[c];
        const float Ec = sE[c];
        ushort4 bw; bw.x = f2b(bv[it].x); bw.y = f2b(bv[it].y); bw.z = f2b(bv[it].z); bw.w = f2b(bv[it].w);
        ushort4 cw; cw.x = f2b(cv[it].x); cw.y = f2b(cv[it].y); cw.z = f2b(cv[it].z); cw.w = f2b(cv[it].w);
        *(ushort4*)&sBrm[rm_e(c, p0)] = bw;
        *(ushort4*)&sCrm[rm_e(c, p0)] = cw;
        sBt[tr_e(p0 + 0, c)] = bw.x;
        sBt[tr_e(p0 + 1, c)] = bw.y;
        sBt[tr_e(p0 + 2, c)] = bw.z;
        sBt[tr_e(p0 + 3, c)] = bw.w;
        sXt[tr_e(p0 + 0, c)] = f2b(xv[it].x * dte);
        sXt[tr_e(p0 + 1, c)] = f2b(xv[it].y * dte);
        sXt[tr_e(p0 + 2, c)] = f2b(xv[it].z * dte);
        sXt[tr_e(p0 + 3, c)] = f2b(xv[it].w * dte);
        // Cs frag-native: elem (i=c, s=p0+j) -> ((kk*4+ti)*64 + lt)*8 + e
        {
            const int kk = p0 >> 5;
            const int ti0 = c >> 4;
            const int lt = ((p0 >> 3) & 3) * 16 + (c & 15);
            const int e0 = p0 & 7;
            ushort4 sw; sw.x = f2b(cv[it].x * Ec); sw.y = f2b(cv[it].y * Ec);
            sw.z = f2b(cv[it].z * Ec); sw.w = f2b(cv[it].w * Ec);
            *(ushort4*)&Csws[chb + (((kk * 4 + ti0) * 64 + lt) << 3) + e0] = sw;
        }
    }
    __syncthreads();

    const f32x4 zero = {0.f, 0.f, 0.f, 0.f};
    // mm1T: D[j][i] = sum_s B[j][s] C[i][s]; mmH: D[s][p] = sum_c B[c][s] (dte X)[c][p]
    f32x4 accT[4] = {zero, zero, zero, zero};
    f32x4 accH[4] = {zero, zero, zero, zero};
    #pragma unroll
    for (int kk = 0; kk < 2; ++kk) {
        const bf16x8 aB = frag_rm(sBrm, w, kk, l);
        const bf16x8 aBt = frag_tr(sBt, w, kk, l);
        #pragma unroll
        for (int t = 0; t < 4; ++t) {
            accT[t] = __builtin_amdgcn_mfma_f32_16x16x32_bf16(aB, frag_rm(sCrm, t, kk, l), accT[t], 0, 0, 0);
            accH[t] = __builtin_amdgcn_mfma_f32_16x16x32_bf16(aBt, frag_tr(sXt, t, kk, l), accH[t], 0, 0, 0);
        }
    }

    const int il = (l >> 4) << 2;
    // M store, fragment-native: lane-contiguous ushort4 per ti
    // element r <-> M[i=ti*16+(l&15)][j=w*16+(l>>4)*4+r]
    const int j0 = w * 16 + il;
    float Rj[4];
    #pragma unroll
    for (int r = 0; r < 4; ++r) Rj[r] = sR[j0 + r];
    #pragma unroll
    for (int ti = 0; ti < 4; ++ti) {
        const int i = ti * 16 + (l & 15);
        const float Ei = sE[i];
        ushort4 m;
        m.x = (i >= j0 + 0) ? f2b(Ei * Rj[0] * accT[ti][0]) : (unsigned short)0;
        m.y = (i >= j0 + 1) ? f2b(Ei * Rj[1] * accT[ti][1]) : (unsigned short)0;
        m.z = (i >= j0 + 2) ? f2b(Ei * Rj[2] * accT[ti][2]) : (unsigned short)0;
        m.w = (i >= j0 + 3) ? f2b(Ei * Rj[3] * accT[ti][3]) : (unsigned short)0;
        *(ushort4*)&Mws[chb + (((ti * 4 + w) * 64 + l) << 2)] = m;
    }
    // h store, fragment-native: elem (p=tp*16+(l&15), s=w*16+il+r)
    {
        const int kk = w >> 1;
        const int q3 = ((w & 1) << 1) | (il >> 3);
        const int e0 = il & 7;
        const int lt = q3 * 16 + (l & 15);
        #pragma unroll
        for (int tp = 0; tp < 4; ++tp) {
            ushort4 o;
            o.x = f2b(accH[tp][0]); o.y = f2b(accH[tp][1]);
            o.z = f2b(accH[tp][2]); o.w = f2b(accH[tp][3]);
            *(ushort4*)&hws[chb + (((kk * 4 + tp) * 64 + lt) << 3) + e0] = o;
        }
    }
}

// ---------------- K2: h_inter = W · h_final (per (bh, p), in-place) ----------------
__global__ __launch_bounds__(256) void ssd_k2(
    unsigned short* __restrict__ hws, const float* __restrict__ dws)
{
    __shared__ __align__(16) unsigned short sHt[64 * 64];  // hf^T [s][c'] tr-swz
    __shared__ __align__(16) unsigned short sW[64 * 64];   // W [c][c'] rm-swz
    __shared__ __align__(16) unsigned short sOut[64 * 64]; // h_inter [s][c] swz
    __shared__ float sI[64];

    const int tid = threadIdx.x;
    const int l = tid & 63;
    const int w = tid >> 6;
    const int bh = blockIdx.x >> 6;
    const int p = blockIdx.x & 63;
    const int tp = p >> 4, p15 = p & 15;

    // issue hf loads: thread -> (chunk cq, s-seg of 16)
    const int cq = tid >> 2;
    const int sseg = (tid & 3) << 4;
    const unsigned fragoff =
        (unsigned)(((((sseg >> 5) * 4 + tp) * 64 + ((sseg >> 3) & 3) * 16 + p15)) << 3);
    const unsigned chbL = ((unsigned)(bh * 64 + cq)) * CHW;
    const uint4 u0 = *(const uint4*)&hws[chbL + fragoff];
    const uint4 u1 = *(const uint4*)&hws[chbL + fragoff + 128];

    // wave0: inclusive cumsum of chunk log-decays
    if (tid < 64) {
        float a = dws[bh * 64 + tid];
        #pragma unroll
        for (int off = 1; off < 64; off <<= 1) {
            float v = __shfl_up(a, off, 64);
            if (tid >= off) a += v;
        }
        sI[tid] = a;
    }
    __syncthreads();

    // W[c][c'] = (c > c') ? exp(I[c-1] - I[c']) : 0  (entries <= 1; underflow -> 0 correct)
    {
        const int c = tid >> 2;
        const int cb = (tid & 3) << 4;
        const float Ic1 = (c > 0) ? sI[c - 1] : 0.f;
        #pragma unroll
        for (int g = 0; g < 4; ++g) {
            ushort4 wv;
            const int c2 = cb + g * 4;
            wv.x = (c > c2 + 0) ? f2b(__expf(Ic1 - sI[c2 + 0])) : (unsigned short)0;
            wv.y = (c > c2 + 1) ? f2b(__expf(Ic1 - sI[c2 + 1])) : (unsigned short)0;
            wv.z = (c > c2 + 2) ? f2b(__expf(Ic1 - sI[c2 + 2])) : (unsigned short)0;
            wv.w = (c > c2 + 3) ? f2b(__expf(Ic1 - sI[c2 + 3])) : (unsigned short)0;
            *(ushort4*)&sW[rm_e(c, c2)] = wv;
        }
    }
    // scatter hf into transposed LDS tile
    {
        const unsigned short* a0 = (const unsigned short*)&u0;
        const unsigned short* a1 = (const unsigned short*)&u1;
        #pragma unroll
        for (int e = 0; e < 8; ++e) {
            sHt[tr_e(sseg + e, cq)] = a0[e];
            sHt[tr_e(sseg + 8 + e, cq)] = a1[e];
        }
    }
    __syncthreads();

    const f32x4 zero = {0.f, 0.f, 0.f, 0.f};
    f32x4 acc[4] = {zero, zero, zero, zero};
    #pragma unroll
    for (int kk = 0; kk < 2; ++kk) {
        const bf16x8 aH = frag_tr(sHt, w, kk, l);
        #pragma unroll
        for (int ti = 0; ti < 4; ++ti)
            acc[ti] = __builtin_amdgcn_mfma_f32_16x16x32_bf16(aH, frag_rm(sW, ti, kk, l), acc[ti], 0, 0, 0);
    }
    // D[row=s][col=c] -> sOut[s][c] (swizzled scalar writes)
    const int il = (l >> 4) << 2;
    #pragma unroll
    for (int ti = 0; ti < 4; ++ti) {
        const int c = ti * 16 + (l & 15);
        #pragma unroll
        for (int r = 0; r < 4; ++r) {
            const int s = w * 16 + il + r;
            sOut[s * 64 + (c ^ ((s & 7) << 3))] = f2b(acc[ti][r]);
        }
    }
    __syncthreads();
    // coalesced copy-out, in-place (same addresses as the load)
    {
        FragU o0, o1;
        #pragma unroll
        for (int e = 0; e < 8; ++e) {
            const int s0 = sseg + e, s1 = sseg + 8 + e;
            o0.s[e] = sOut[s0 * 64 + (cq ^ ((s0 & 7) << 3))];
            o1.s[e] = sOut[s1 * 64 + (cq ^ ((s1 & 7) << 3))];
        }
        *(uint4*)&hws[chbL + fragoff] = o0.u;
        *(uint4*)&hws[chbL + fragoff + 128] = o1.u;
    }
}

// ---------------- K3: LDS-free, barrier-free ----------------
__global__ __launch_bounds__(256) void ssd_k3(
    const float* __restrict__ Xg, const unsigned short* __restrict__ Mws,
    const unsigned short* __restrict__ Csws, const unsigned short* __restrict__ hws,
    float* __restrict__ Yg)
{
    const int tid = threadIdx.x;
    const int l = tid & 63;
    const int w = tid >> 6;
    const int n = blockIdx.x & (NC - 1);
    const int h = (blockIdx.x >> 6) & (NH - 1);
    const int b = blockIdx.x >> 10;
    const int row0 = b * LSEQ + n * 64;
    const unsigned chb = (unsigned)blockIdx.x * CHW;
    const int i15 = l & 15;
    const int p = w * 16 + i15;

    // A-frags: X^T (scalar fp32 loads, lanes coalesce 64B rows) and h (uint4 frag-native)
    bf16x8 aX[2], aH[2];
    #pragma unroll
    for (int kk = 0; kk < 2; ++kk) {
        const int c0 = kk * 32 + ((l >> 4) << 3);
        bf16x8 x;
        #pragma unroll
        for (int e = 0; e < 8; ++e)
            x[e] = (__bf16)Xg[((unsigned)(row0 + c0 + e) * NH + h) * 64 + p];
        aX[kk] = x;
        FragU f; f.u = *(const uint4*)&hws[chb + (((kk * 4 + w) * 64 + l) << 3)];
        aH[kk] = f.b;
    }

    const f32x4 zero = {0.f, 0.f, 0.f, 0.f};
    f32x4 accY[4] = {zero, zero, zero, zero};
    f32x4 accI[4] = {zero, zero, zero, zero};
    #pragma unroll
    for (int kk = 0; kk < 2; ++kk) {
        const int j0 = kk * 32 + ((l >> 4) << 3);
        const int wj = j0 >> 4;
        const int q = (j0 >> 2) & 3;
        #pragma unroll
        for (int ti = 0; ti < 4; ++ti) {
            FragU mf, cf;
            *(ushort4*)&mf.s[0] = *(const ushort4*)&Mws[chb + (((ti * 4 + wj) * 64 + q * 16 + i15) << 2)];
            *(ushort4*)&mf.s[4] = *(const ushort4*)&Mws[chb + (((ti * 4 + wj) * 64 + (q + 1) * 16 + i15) << 2)];
            cf.u = *(const uint4*)&Csws[chb + (((kk * 4 + ti) * 64 + l) << 3)];
            accY[ti] = __builtin_amdgcn_mfma_f32_16x16x32_bf16(aX[kk], mf.b, accY[ti], 0, 0, 0);
            accI[ti] = __builtin_amdgcn_mfma_f32_16x16x32_bf16(aH[kk], cf.b, accI[ti], 0, 0, 0);
        }
    }

    const int pbase = w * 16 + ((l >> 4) << 2);
    #pragma unroll
    for (int ti = 0; ti < 4; ++ti) {
        const int i = ti * 16 + i15;
        float4 o;
        o.x = accY[ti][0] + accI[ti][0];
        o.y = accY[ti][1] + accI[ti][1];
        o.z = accY[ti][2] + accI[ti][2];
        o.w = accY[ti][3] + accI[ti][3];
        *(float4*)&Yg[((unsigned)(row0 + i) * NH + h) * 64 + pbase] = o;
    }
}

extern "C" void kernel_launch(void* const* d_in, const int* in_sizes, int n_in,
                              void* d_out, int out_size, void* d_ws, size_t ws_size,
                              hipStream_t stream) {
    const float* X = (const float*)d_in[0];
    const float* A = (const float*)d_in[1];
    const float* Bm = (const float*)d_in[2];
    const float* Cm = (const float*)d_in[3];
    float* Y = (float*)d_out;
    unsigned short* hws = (unsigned short*)d_ws;        // 16.8 MB
    unsigned short* Mws = hws + TILE_USHORTS;           // 16.8 MB
    unsigned short* Csws = Mws + TILE_USHORTS;          // 16.8 MB
    float* dws = (float*)(Csws + TILE_USHORTS);         // 8 KB (log chunk decays)

    ssd_k1<<<NCH, 256, 0, stream>>>(X, A, Bm, Cm, hws, Mws, Csws, dws);
    ssd_k2<<<NCH, 256, 0, stream>>>(hws, dws);
    ssd_k3<<<NCH, 256, 0, stream>>>(X, Mws, Csws, hws, Y);
}

// Round 6
// 75.213 us; speedup vs baseline: 1.1206x; 1.1206x over previous
//
#include <hip/hip_runtime.h>

// Mamba-2 SSD forward. B=2, L=4096, H=16, P=S=64, chunk=64, n=64 chunks.
// K1: per chunk: M = L∘(C·B^T), Cs = dfs∘C, h_final^T, chunk log-decay.
//     All ws tiles stored in MFMA-fragment-native order (coalesced both ways).
// K2: element-wise inter-chunk scan on frag-native hws (coalesced, 4-deep pipeline).
// K3: LDS-free, barrier-free: Y^T = X^T·M^T + h^T·Cs^T, float4 stores.

#define BSZ 2
#define LSEQ 4096
#define NH 16
#define NC 64
#define NCH (BSZ * NH * NC)      // 2048 chunk tasks
#define SCAN_G 8
#define CHW 4096                 // ushort elems per chunk ws tile
#define TILE_USHORTS ((size_t)NCH * CHW)

typedef float f32x4 __attribute__((ext_vector_type(4)));
typedef __bf16 bf16x8 __attribute__((ext_vector_type(8)));

union FragU { uint4 u; bf16x8 b; unsigned short s[8]; };

__device__ __forceinline__ unsigned short f2b(float x) {
    union { float f; unsigned u; } c; c.f = x;
    unsigned r = c.u + 0x7fffu + ((c.u >> 16) & 1u);   // RNE bf16
    return (unsigned short)(r >> 16);
}
__device__ __forceinline__ float b2f(unsigned short v) {
    union { unsigned u; float f; } c; c.u = ((unsigned)v) << 16;
    return c.f;
}

// LDS element-index swizzles, 64 ushort per row
__device__ __forceinline__ int rm_e(int row, int k) { return row * 64 + (k ^ ((row & 7) << 3)); }
__device__ __forceinline__ int tr_e(int row, int k) { return row * 64 + (k ^ (((row >> 1) & 7) << 3)); }

__device__ __forceinline__ bf16x8 frag_rm(const unsigned short* buf, int tile, int kk, int l) {
    FragU f; f.u = *(const uint4*)&buf[rm_e(tile * 16 + (l & 15), kk * 32 + ((l >> 4) << 3))];
    return f.b;
}
__device__ __forceinline__ bf16x8 frag_tr(const unsigned short* buf, int tile, int kk, int l) {
    FragU f; f.u = *(const uint4*)&buf[tr_e(tile * 16 + (l & 15), kk * 32 + ((l >> 4) << 3))];
    return f.b;
}

// ---------------- K1 ----------------
__global__ __launch_bounds__(256) void ssd_k1(
    const float* __restrict__ Xg, const float* __restrict__ Ag,
    const float* __restrict__ Bg, const float* __restrict__ Cg,
    unsigned short* __restrict__ hws, unsigned short* __restrict__ Mws,
    unsigned short* __restrict__ Csws, float* __restrict__ dws)
{
    __shared__ __align__(16) unsigned short sBrm[64 * 64];  // B [j][s]
    __shared__ __align__(16) unsigned short sCrm[64 * 64];  // C [i][s]
    __shared__ __align__(16) unsigned short sBt[64 * 64];   // B^T [s][c]
    __shared__ __align__(16) unsigned short sXt[64 * 64];   // (dte∘X)^T [p][c]
    __shared__ float sE[64], sR[64], sDte[64];

    const int tid = threadIdx.x;
    const int l = tid & 63;
    const int w = tid >> 6;
    const int n = blockIdx.x & (NC - 1);
    const int h = (blockIdx.x >> 6) & (NH - 1);
    const int b = blockIdx.x >> 10;
    const int row0 = b * LSEQ + n * 64;
    const unsigned chb = (unsigned)blockIdx.x * CHW;

    // issue global loads early
    float4 xv[4], bv[4], cv[4];
    const int p0 = (tid & 15) * 4;
    #pragma unroll
    for (int it = 0; it < 4; ++it) {
        const int c = (tid >> 4) + it * 16;
        const unsigned g = ((unsigned)(row0 + c) * NH + h) * 64 + p0;
        xv[it] = *(const float4*)&Xg[g];
        bv[it] = *(const float4*)&Bg[g];
        cv[it] = *(const float4*)&Cg[g];
    }
    // wave0: inclusive cumsum of A, decay factors
    if (tid < 64) {
        float a = Ag[(unsigned)(row0 + tid) * NH + h];
        #pragma unroll
        for (int off = 1; off < 64; off <<= 1) {
            float v = __shfl_up(a, off, 64);
            if (tid >= off) a += v;
        }
        const float a63 = __shfl(a, 63, 64);
        sE[tid] = __expf(a);
        sR[tid] = __expf(-a);
        sDte[tid] = __expf(a63 - a);
        if (tid == 63) dws[blockIdx.x] = a63;       // log chunk decay
    }
    __syncthreads();

    // stage LDS tiles + write Cs (= E[i]∘C) to ws in fragment-native order
    #pragma unroll
    for (int it = 0; it < 4; ++it) {
        const int c = (tid >> 4) + it * 16;
        const float dte = sDte[c];
        const float Ec = sE[c];
        ushort4 bw; bw.x = f2b(bv[it].x); bw.y = f2b(bv[it].y); bw.z = f2b(bv[it].z); bw.w = f2b(bv[it].w);
        ushort4 cw; cw.x = f2b(cv[it].x); cw.y = f2b(cv[it].y); cw.z = f2b(cv[it].z); cw.w = f2b(cv[it].w);
        *(ushort4*)&sBrm[rm_e(c, p0)] = bw;
        *(ushort4*)&sCrm[rm_e(c, p0)] = cw;
        sBt[tr_e(p0 + 0, c)] = bw.x;
        sBt[tr_e(p0 + 1, c)] = bw.y;
        sBt[tr_e(p0 + 2, c)] = bw.z;
        sBt[tr_e(p0 + 3, c)] = bw.w;
        sXt[tr_e(p0 + 0, c)] = f2b(xv[it].x * dte);
        sXt[tr_e(p0 + 1, c)] = f2b(xv[it].y * dte);
        sXt[tr_e(p0 + 2, c)] = f2b(xv[it].z * dte);
        sXt[tr_e(p0 + 3, c)] = f2b(xv[it].w * dte);
        // Cs frag-native: elem (i=c, s=p0+j) -> ((kk*4+ti)*64 + lt)*8 + e
        {
            const int kk = p0 >> 5;
            const int ti0 = c >> 4;
            const int lt = ((p0 >> 3) & 3) * 16 + (c & 15);
            const int e0 = p0 & 7;
            ushort4 sw; sw.x = f2b(cv[it].x * Ec); sw.y = f2b(cv[it].y * Ec);
            sw.z = f2b(cv[it].z * Ec); sw.w = f2b(cv[it].w * Ec);
            *(ushort4*)&Csws[chb + (((kk * 4 + ti0) * 64 + lt) << 3) + e0] = sw;
        }
    }
    __syncthreads();

    const f32x4 zero = {0.f, 0.f, 0.f, 0.f};
    // mm1T: D[j][i] = sum_s B[j][s] C[i][s]; mmH: D[s][p] = sum_c B[c][s] (dte X)[c][p]
    f32x4 accT[4] = {zero, zero, zero, zero};
    f32x4 accH[4] = {zero, zero, zero, zero};
    #pragma unroll
    for (int kk = 0; kk < 2; ++kk) {
        const bf16x8 aB = frag_rm(sBrm, w, kk, l);
        const bf16x8 aBt = frag_tr(sBt, w, kk, l);
        #pragma unroll
        for (int t = 0; t < 4; ++t) {
            accT[t] = __builtin_amdgcn_mfma_f32_16x16x32_bf16(aB, frag_rm(sCrm, t, kk, l), accT[t], 0, 0, 0);
            accH[t] = __builtin_amdgcn_mfma_f32_16x16x32_bf16(aBt, frag_tr(sXt, t, kk, l), accH[t], 0, 0, 0);
        }
    }

    const int il = (l >> 4) << 2;
    // M store, fragment-native: lane-contiguous ushort4 per ti
    const int j0 = w * 16 + il;
    float Rj[4];
    #pragma unroll
    for (int r = 0; r < 4; ++r) Rj[r] = sR[j0 + r];
    #pragma unroll
    for (int ti = 0; ti < 4; ++ti) {
        const int i = ti * 16 + (l & 15);
        const float Ei = sE[i];
        ushort4 m;
        m.x = (i >= j0 + 0) ? f2b(Ei * Rj[0] * accT[ti][0]) : (unsigned short)0;
        m.y = (i >= j0 + 1) ? f2b(Ei * Rj[1] * accT[ti][1]) : (unsigned short)0;
        m.z = (i >= j0 + 2) ? f2b(Ei * Rj[2] * accT[ti][2]) : (unsigned short)0;
        m.w = (i >= j0 + 3) ? f2b(Ei * Rj[3] * accT[ti][3]) : (unsigned short)0;
        *(ushort4*)&Mws[chb + (((ti * 4 + w) * 64 + l) << 2)] = m;
    }
    // h store, fragment-native: elem (p=tp*16+(l&15), s=w*16+il+r)
    {
        const int kk = w >> 1;
        const int q3 = ((w & 1) << 1) | (il >> 3);
        const int e0 = il & 7;
        const int lt = q3 * 16 + (l & 15);
        #pragma unroll
        for (int tp = 0; tp < 4; ++tp) {
            ushort4 o;
            o.x = f2b(accH[tp][0]); o.y = f2b(accH[tp][1]);
            o.z = f2b(accH[tp][2]); o.w = f2b(accH[tp][3]);
            *(ushort4*)&hws[chb + (((kk * 4 + tp) * 64 + lt) << 3) + e0] = o;
        }
    }
}

// ---------------- K2: element-wise scan over chunks (in-place, coalesced) ----------------
// hws layout is per-chunk tiles of 2048 uints; the scan is element-wise across chunks,
// so it is layout-transparent. 4-deep load pipeline hides L2/LLC latency.
__global__ __launch_bounds__(256) void ssd_scan(unsigned short* __restrict__ hws,
                                                const float* __restrict__ dws)
{
    __shared__ float sD[NC];
    const int tid = threadIdx.x;
    const int bh = blockIdx.x / SCAN_G;
    const int g = blockIdx.x % SCAN_G;
    if (tid < NC) sD[tid] = __expf(dws[bh * NC + tid]);   // chunk decay from log
    __syncthreads();

    unsigned* hw32 = (unsigned*)hws;
    const unsigned base = (unsigned)bh * NC * 2048u + g * 256u + tid;

    unsigned buf[4];
    #pragma unroll
    for (int j = 0; j < 4; ++j) buf[j] = hw32[base + j * 2048u];

    float cx = 0.f, cy = 0.f;
    #pragma unroll 4
    for (int c = 0; c < NC; ++c) {
        const unsigned cur = buf[c & 3];
        if (c + 4 < NC) buf[c & 3] = hw32[base + (unsigned)(c + 4) * 2048u];
        hw32[base + (unsigned)c * 2048u] = (unsigned)f2b(cx) | ((unsigned)f2b(cy) << 16);
        const float d = sD[c];
        cx = d * cx + b2f((unsigned short)(cur & 0xffffu));
        cy = d * cy + b2f((unsigned short)(cur >> 16));
    }
}

// ---------------- K3: LDS-free, barrier-free ----------------
__global__ __launch_bounds__(256) void ssd_k3(
    const float* __restrict__ Xg, const unsigned short* __restrict__ Mws,
    const unsigned short* __restrict__ Csws, const unsigned short* __restrict__ hws,
    float* __restrict__ Yg)
{
    const int tid = threadIdx.x;
    const int l = tid & 63;
    const int w = tid >> 6;
    const int n = blockIdx.x & (NC - 1);
    const int h = (blockIdx.x >> 6) & (NH - 1);
    const int b = blockIdx.x >> 10;
    const int row0 = b * LSEQ + n * 64;
    const unsigned chb = (unsigned)blockIdx.x * CHW;
    const int i15 = l & 15;
    const int p = w * 16 + i15;

    // A-frags: X^T (scalar fp32 loads, lanes coalesce 64B rows) and h (uint4 frag-native)
    bf16x8 aX[2], aH[2];
    #pragma unroll
    for (int kk = 0; kk < 2; ++kk) {
        const int c0 = kk * 32 + ((l >> 4) << 3);
        bf16x8 x;
        #pragma unroll
        for (int e = 0; e < 8; ++e)
            x[e] = (__bf16)Xg[((unsigned)(row0 + c0 + e) * NH + h) * 64 + p];
        aX[kk] = x;
        FragU f; f.u = *(const uint4*)&hws[chb + (((kk * 4 + w) * 64 + l) << 3)];
        aH[kk] = f.b;
    }

    const f32x4 zero = {0.f, 0.f, 0.f, 0.f};
    f32x4 accY[4] = {zero, zero, zero, zero};
    f32x4 accI[4] = {zero, zero, zero, zero};
    #pragma unroll
    for (int kk = 0; kk < 2; ++kk) {
        const int j0 = kk * 32 + ((l >> 4) << 3);
        const int wj = j0 >> 4;
        const int q = (j0 >> 2) & 3;
        #pragma unroll
        for (int ti = 0; ti < 4; ++ti) {
            FragU mf, cf;
            *(ushort4*)&mf.s[0] = *(const ushort4*)&Mws[chb + (((ti * 4 + wj) * 64 + q * 16 + i15) << 2)];
            *(ushort4*)&mf.s[4] = *(const ushort4*)&Mws[chb + (((ti * 4 + wj) * 64 + (q + 1) * 16 + i15) << 2)];
            cf.u = *(const uint4*)&Csws[chb + (((kk * 4 + ti) * 64 + l) << 3)];
            accY[ti] = __builtin_amdgcn_mfma_f32_16x16x32_bf16(aX[kk], mf.b, accY[ti], 0, 0, 0);
            accI[ti] = __builtin_amdgcn_mfma_f32_16x16x32_bf16(aH[kk], cf.b, accI[ti], 0, 0, 0);
        }
    }

    const int pbase = w * 16 + ((l >> 4) << 2);
    #pragma unroll
    for (int ti = 0; ti < 4; ++ti) {
        const int i = ti * 16 + i15;
        float4 o;
        o.x = accY[ti][0] + accI[ti][0];
        o.y = accY[ti][1] + accI[ti][1];
        o.z = accY[ti][2] + accI[ti][2];
        o.w = accY[ti][3] + accI[ti][3];
        *(float4*)&Yg[((unsigned)(row0 + i) * NH + h) * 64 + pbase] = o;
    }
}

extern "C" void kernel_launch(void* const* d_in, const int* in_sizes, int n_in,
                              void* d_out, int out_size, void* d_ws, size_t ws_size,
                              hipStream_t stream) {
    const float* X = (const float*)d_in[0];
    const float* A = (const float*)d_in[1];
    const float* Bm = (const float*)d_in[2];
    const float* Cm = (const float*)d_in[3];
    float* Y = (float*)d_out;
    unsigned short* hws = (unsigned short*)d_ws;        // 16.8 MB
    unsigned short* Mws = hws + TILE_USHORTS;           // 16.8 MB
    unsigned short* Csws = Mws + TILE_USHORTS;          // 16.8 MB
    float* dws = (float*)(Csws + TILE_USHORTS);         // 8 KB (log chunk decays)

    ssd_k1<<<NCH, 256, 0, stream>>>(X, A, Bm, Cm, hws, Mws, Csws, dws);
    ssd_scan<<<BSZ * NH * SCAN_G, 256, 0, stream>>>(hws, dws);
    ssd_k3<<<NCH, 256, 0, stream>>>(X, Mws, Csws, hws, Y);
}